// Round 2
// baseline (31713.098 us; speedup 1.0000x reference)
//
#include <hip/hip_runtime.h>
#include <hip/hip_bf16.h>
#include <stdint.h>

#define T_SEQ 8192
#define DIMS  2048
#define VOCAB 512
#define NB    256
#define TPB   256
#define GS    ((size_t)VOCAB * DIMS)

typedef unsigned short u16;
typedef unsigned int   uint32;
typedef unsigned long long u64;

__device__ __forceinline__ float lo2f(uint32 u) { return __uint_as_float(u << 16); }
__device__ __forceinline__ float hi2f(uint32 u) { return __uint_as_float(u & 0xffff0000u); }

// ---------------------------------------------------------------- X = Wx.T + bx
// X[v][d] = Wx[d][v] + bx[d] (all f32). Coalesced read of Wx, scattered write of X.
__global__ __launch_bounds__(256) void k_build_x(const float* __restrict__ Wx,
                                                 const float* __restrict__ bx,
                                                 float* __restrict__ X) {
  int i = blockIdx.x * 256 + threadIdx.x;      // i = d*VOCAB + v
  int v = i & (VOCAB - 1);
  int d = i >> 9;
  X[(size_t)v * DIMS + d] = Wx[i] + bx[d];
}

// ---------------------------------------------------------------- G_g = X @ Wg.T + bwg
// 64v x 64j tile, BK=32, fp32 accumulate (G feeds an 8192-step recurrence).
__global__ __launch_bounds__(256) void k_gate_gemm(const float* __restrict__ X,
                                                   const float* __restrict__ Wg,
                                                   const float* __restrict__ bw,
                                                   float* __restrict__ Gout) {
  __shared__ float Xs[32][64];
  __shared__ float Ws[32][64];
  const int v0 = blockIdx.y * 64;
  const int j0 = blockIdx.x * 64;
  const int tid = threadIdx.x;
  const int tx = tid & 15, ty = tid >> 4;
  float acc[4][4] = {{0.f}};
  for (int k0 = 0; k0 < DIMS; k0 += 32) {
    const int r = tid >> 2, q = tid & 3;
    {
      const float* src = X + (size_t)(v0 + r) * DIMS + k0 + q * 8;
      float4 a = ((const float4*)src)[0];
      float4 b = ((const float4*)src)[1];
      Xs[q*8+0][r]=a.x; Xs[q*8+1][r]=a.y; Xs[q*8+2][r]=a.z; Xs[q*8+3][r]=a.w;
      Xs[q*8+4][r]=b.x; Xs[q*8+5][r]=b.y; Xs[q*8+6][r]=b.z; Xs[q*8+7][r]=b.w;
      const float* wsrc = Wg + (size_t)(j0 + r) * DIMS + k0 + q * 8;
      float4 c = ((const float4*)wsrc)[0];
      float4 e = ((const float4*)wsrc)[1];
      Ws[q*8+0][r]=c.x; Ws[q*8+1][r]=c.y; Ws[q*8+2][r]=c.z; Ws[q*8+3][r]=c.w;
      Ws[q*8+4][r]=e.x; Ws[q*8+5][r]=e.y; Ws[q*8+6][r]=e.z; Ws[q*8+7][r]=e.w;
    }
    __syncthreads();
    #pragma unroll
    for (int k = 0; k < 32; ++k) {
      float xa[4], wb[4];
      *(float4*)xa = *(const float4*)&Xs[k][ty*4];
      *(float4*)wb = *(const float4*)&Ws[k][tx*4];
      #pragma unroll
      for (int a = 0; a < 4; ++a)
        #pragma unroll
        for (int b = 0; b < 4; ++b)
          acc[a][b] = fmaf(xa[a], wb[b], acc[a][b]);
    }
    __syncthreads();
  }
  #pragma unroll
  for (int a = 0; a < 4; ++a)
    #pragma unroll
    for (int b = 0; b < 4; ++b)
      Gout[(size_t)(v0 + ty*4 + a) * DIMS + j0 + tx*4 + b] =
          acc[a][b] + bw[j0 + tx*4 + b];
}

// ---------------------------------------------------------------- recurrence
template <typename HS> __device__ __forceinline__ void store_h(HS* hs, size_t idx, float v);
template <> __device__ __forceinline__ void store_h<float>(float* hs, size_t idx, float v) { hs[idx] = v; }
template <> __device__ __forceinline__ void store_h<u16>(u16* hs, size_t idx, float v) {
  __hip_bfloat16 b = __float2bfloat16(v);
  hs[idx] = *reinterpret_cast<u16*>(&b);
}

// Persistent kernel: 256 blocks (1/CU), block b owns output dims [8b, 8b+8) of all 4 gates.
// U rows live in VGPRs as fp32. h published as (tag<<32 | f32bits) u64 atomics,
// double-buffered; readers poll tags. No global barrier, no fences in the loop.
template <typename HS>
__global__ __launch_bounds__(256, 1) void k_lstm(
    const int* __restrict__ tokens,
    const float* __restrict__ G,
    u64* hbuf,
    HS* __restrict__ hs,
    const float* __restrict__ Uf, const float* __restrict__ Ui,
    const float* __restrict__ Uc, const float* __restrict__ Uo,
    const float* __restrict__ bUf, const float* __restrict__ bUi,
    const float* __restrict__ bUc, const float* __restrict__ bUo) {
  __shared__ float h_s[DIMS];
  __shared__ float gates_s[4][8];
  const int tid = threadIdx.x;
  const int blk = blockIdx.x;
  const int wave = tid >> 6;            // 0..3 -> gate f,i,c,o
  const int lane = tid & 63;
  const int j0 = blk * 8;

  const float* U = (wave == 0) ? Uf : (wave == 1) ? Ui : (wave == 2) ? Uc : Uo;
  // lane covers k-pairs p = lane + 64*i (k = 2p, 2p+1); weights fp32 in regs.
  float2 w[8][16];
  {
    const float2* ub = (const float2*)U;
    #pragma unroll
    for (int r = 0; r < 8; ++r) {
      const float2* rowp = ub + (size_t)(j0 + r) * (DIMS / 2);
      #pragma unroll
      for (int i = 0; i < 16; ++i) w[r][i] = rowp[lane + 64 * i];
    }
  }
  float creg = 0.f;
  float b0 = 0.f, b1 = 0.f, b2 = 0.f, b3 = 0.f;
  float g0 = 0.f, g1 = 0.f, g2 = 0.f, g3 = 0.f;
  int tok_nx = 0;
  if (tid < 8) {
    const int j = j0 + tid;
    b0 = bUf[j]; b1 = bUi[j]; b2 = bUc[j]; b3 = bUo[j];
    tok_nx = tokens[0];
    g0 = G[0 * GS + (size_t)tok_nx * DIMS + j];
    g1 = G[1 * GS + (size_t)tok_nx * DIMS + j];
    g2 = G[2 * GS + (size_t)tok_nx * DIMS + j];
    g3 = G[3 * GS + (size_t)tok_nx * DIMS + j];
    // publish h0 = 0 with tag 0; sentinel into buffer 1 (defense vs stale tags).
    __hip_atomic_store(&hbuf[j], 0ull, __ATOMIC_RELAXED, __HIP_MEMORY_SCOPE_AGENT);
    __hip_atomic_store(&hbuf[DIMS + j], 0x8000000000000000ull,
                       __ATOMIC_RELAXED, __HIP_MEMORY_SCOPE_AGENT);
  }
  #pragma unroll 1
  for (int t = 0; t < T_SEQ; ++t) {
    if (tid < 8) {
      int tn = (t + 1 < T_SEQ) ? t + 1 : T_SEQ - 1;
      tok_nx = tokens[tn];               // prefetch next token (hidden behind step)
    }
    { // stage h_t: poll tags, 8 u64 per thread, LLC-direct
      u64* hsrc = hbuf + (size_t)(t & 1) * DIMS;
      u64 u[8];
      const uint32 want = (uint32)t;
      bool ok;
      do {
        ok = true;
        #pragma unroll
        for (int q = 0; q < 8; ++q)
          u[q] = __hip_atomic_load(&hsrc[tid + 256 * q], __ATOMIC_RELAXED,
                                   __HIP_MEMORY_SCOPE_AGENT);
        #pragma unroll
        for (int q = 0; q < 8; ++q)
          ok = ok && ((uint32)(u[q] >> 32) == want);
        if (!ok) __builtin_amdgcn_s_sleep(1);
      } while (!ok);
      #pragma unroll
      for (int q = 0; q < 8; ++q)
        h_s[tid + 256 * q] = __uint_as_float((uint32)u[q]);
    }
    __syncthreads();
    // 8 dot products of length 2048 per wave, fp32
    float2 acc2[8];
    #pragma unroll
    for (int r = 0; r < 8; ++r) acc2[r] = make_float2(0.f, 0.f);
    const float2* h2 = (const float2*)h_s;
    #pragma unroll
    for (int i = 0; i < 16; ++i) {
      float2 hv = h2[lane + 64 * i];
      #pragma unroll
      for (int r = 0; r < 8; ++r) {
        acc2[r].x = fmaf(w[r][i].x, hv.x, acc2[r].x);
        acc2[r].y = fmaf(w[r][i].y, hv.y, acc2[r].y);
      }
    }
    float acc[8];
    #pragma unroll
    for (int r = 0; r < 8; ++r) acc[r] = acc2[r].x + acc2[r].y;
    #pragma unroll
    for (int d = 32; d; d >>= 1) {
      #pragma unroll
      for (int r = 0; r < 8; ++r) acc[r] += __shfl_xor(acc[r], d, 64);
    }
    if (lane == 0) {
      #pragma unroll
      for (int r = 0; r < 8; ++r) gates_s[wave][r] = acc[r];
    }
    __syncthreads();
    if (tid < 8) {
      const int j = j0 + tid;
      const float yf = gates_s[0][tid] + b0 + g0;
      const float yi = gates_s[1][tid] + b1 + g1;
      const float yc = gates_s[2][tid] + b2 + g2;
      const float yo = gates_s[3][tid] + b3 + g3;
      const float fg = 1.f / (1.f + __expf(-yf));
      const float ig = 1.f / (1.f + __expf(-yi));
      const float cn = 1.f - 2.f / (1.f + __expf(2.f * yc));
      const float og = 1.f / (1.f + __expf(-yo));
      creg = fg * creg + ig * cn;
      const float th = 1.f - 2.f / (1.f + __expf(2.f * creg));
      const float hv = og * th;
      u64 pack = ((u64)(uint32)(t + 1) << 32) | (u64)__float_as_uint(hv);
      __hip_atomic_store(&hbuf[(size_t)((t + 1) & 1) * DIMS + j], pack,
                         __ATOMIC_RELAXED, __HIP_MEMORY_SCOPE_AGENT);
      store_h<HS>(hs, (size_t)t * DIMS + j, hv);
      g0 = G[0 * GS + (size_t)tok_nx * DIMS + j];   // prefetch gates for t+1
      g1 = G[1 * GS + (size_t)tok_nx * DIMS + j];
      g2 = G[2 * GS + (size_t)tok_nx * DIMS + j];
      g3 = G[3 * GS + (size_t)tok_nx * DIMS + j];
    }
    // no trailing sync needed: next staging self-synchronizes via tag polls,
    // and gates_s writes at t+1 happen only after that poll passes.
  }
}

// ---------------------------------------------------------------- logits = hs @ V.T + bv
template <typename HS> __device__ __forceinline__ void load8(const HS* p, float* o);
template <> __device__ __forceinline__ void load8<float>(const float* p, float* o) {
  float4 a = ((const float4*)p)[0], b = ((const float4*)p)[1];
  o[0]=a.x; o[1]=a.y; o[2]=a.z; o[3]=a.w; o[4]=b.x; o[5]=b.y; o[6]=b.z; o[7]=b.w;
}
template <> __device__ __forceinline__ void load8<u16>(const u16* p, float* o) {
  uint4 u = *(const uint4*)p;
  o[0]=lo2f(u.x); o[1]=hi2f(u.x); o[2]=lo2f(u.y); o[3]=hi2f(u.y);
  o[4]=lo2f(u.z); o[5]=hi2f(u.z); o[6]=lo2f(u.w); o[7]=hi2f(u.w);
}

template <typename HS>
__global__ __launch_bounds__(256) void k_out_gemm(const HS* __restrict__ hs,
                                                  const float* __restrict__ V,
                                                  const float* __restrict__ bvb,
                                                  float* __restrict__ logits) {
  __shared__ float As[32][64];
  __shared__ float Bs[32][128];
  const int t0 = blockIdx.x * 64;
  const int v0 = blockIdx.y * 128;
  const int tid = threadIdx.x;
  const int tx = tid & 15, ty = tid >> 4;
  float acc[4][8] = {{0.f}};
  for (int k0 = 0; k0 < DIMS; k0 += 32) {
    {
      const int r = tid >> 2, q = tid & 3;
      float o8[8];
      load8<HS>(hs + (size_t)(t0 + r) * DIMS + k0 + q * 8, o8);
      #pragma unroll
      for (int s = 0; s < 8; ++s) As[q*8+s][r] = o8[s];
      const int rb = tid >> 1, c0 = (tid & 1) * 2;
      #pragma unroll
      for (int c = 0; c < 2; ++c) {
        float p8[8];
        load8<float>(V + (size_t)(v0 + rb) * DIMS + k0 + (c0 + c) * 8, p8);
        #pragma unroll
        for (int s = 0; s < 8; ++s) Bs[(c0+c)*8+s][rb] = p8[s];
      }
    }
    __syncthreads();
    #pragma unroll
    for (int k = 0; k < 32; ++k) {
      float av[4], bw8[8];
      *(float4*)av = *(const float4*)&As[k][ty*4];
      *(float4*)&bw8[0] = *(const float4*)&Bs[k][tx*8];
      *(float4*)&bw8[4] = *(const float4*)&Bs[k][tx*8+4];
      #pragma unroll
      for (int a = 0; a < 4; ++a)
        #pragma unroll
        for (int b = 0; b < 8; ++b)
          acc[a][b] = fmaf(av[a], bw8[b], acc[a][b]);
    }
    __syncthreads();
  }
  #pragma unroll
  for (int a = 0; a < 4; ++a)
    #pragma unroll
    for (int b = 0; b < 8; ++b)
      logits[(size_t)(t0 + ty*4 + a) * VOCAB + v0 + tx*8 + b] =
          acc[a][b] + bvb[v0 + tx*8 + b];
}

// ---------------------------------------------------------------- log_softmax rows (in-place)
__global__ __launch_bounds__(256) void k_logsoftmax(float* __restrict__ logits) {
  const int t = blockIdx.x;
  const int tid = threadIdx.x;
  float* row = logits + (size_t)t * VOCAB;
  float x0 = row[tid], x1 = row[tid + 256];
  float m = fmaxf(x0, x1);
  #pragma unroll
  for (int d = 32; d; d >>= 1) m = fmaxf(m, __shfl_xor(m, d, 64));
  __shared__ float r1[4], r2[4];
  if ((tid & 63) == 0) r1[tid >> 6] = m;
  __syncthreads();
  m = fmaxf(fmaxf(r1[0], r1[1]), fmaxf(r1[2], r1[3]));
  float s = __expf(x0 - m) + __expf(x1 - m);
  #pragma unroll
  for (int d = 32; d; d >>= 1) s += __shfl_xor(s, d, 64);
  if ((tid & 63) == 0) r2[tid >> 6] = s;
  __syncthreads();
  s = r2[0] + r2[1] + r2[2] + r2[3];
  const float lse = m + __logf(s);
  row[tid] = x0 - lse;
  row[tid + 256] = x1 - lse;
}

// ----------------------------------------------------------------
extern "C" void kernel_launch(void* const* d_in, const int* in_sizes, int n_in,
                              void* d_out, int out_size, void* d_ws, size_t ws_size,
                              hipStream_t stream) {
  const int*   tokens = (const int*)d_in[0];
  const float* Wx  = (const float*)d_in[1];
  const float* bx  = (const float*)d_in[2];
  const float* Uf  = (const float*)d_in[3];
  const float* bUf = (const float*)d_in[4];
  const float* Wf  = (const float*)d_in[5];
  const float* bwf = (const float*)d_in[6];
  const float* Ui  = (const float*)d_in[7];
  const float* bUi = (const float*)d_in[8];
  const float* Wi  = (const float*)d_in[9];
  const float* bwi = (const float*)d_in[10];
  const float* Uc  = (const float*)d_in[11];
  const float* bUc = (const float*)d_in[12];
  const float* Wc  = (const float*)d_in[13];
  const float* bwc = (const float*)d_in[14];
  const float* Uo  = (const float*)d_in[15];
  const float* bUo = (const float*)d_in[16];
  const float* Wo  = (const float*)d_in[17];
  const float* bwo = (const float*)d_in[18];
  const float* V   = (const float*)d_in[19];
  const float* bv  = (const float*)d_in[20];

  char* ws = (char*)d_ws;
  float* X = (float*)ws;                                   // 4 MiB
  float* G = (float*)(ws + 4194304ull);                    // 16 MiB
  u64* hbuf = (u64*)(ws + 20971520ull);                    // 32 KiB
  char* rest = ws + 21004288ull;
  const bool f32path = ws_size >= 88113152ull;             // + hs f32 (64 MiB)

  k_build_x<<<dim3((DIMS * VOCAB) / 256), dim3(256), 0, stream>>>(Wx, bx, X);
  dim3 gg(DIMS / 64, VOCAB / 64);
  k_gate_gemm<<<gg, dim3(256), 0, stream>>>(X, Wf, bwf, G + 0 * GS);
  k_gate_gemm<<<gg, dim3(256), 0, stream>>>(X, Wi, bwi, G + 1 * GS);
  k_gate_gemm<<<gg, dim3(256), 0, stream>>>(X, Wc, bwc, G + 2 * GS);
  k_gate_gemm<<<gg, dim3(256), 0, stream>>>(X, Wo, bwo, G + 3 * GS);

  float* logits = (float*)d_out;   // logits built in d_out, log_softmax in-place
  if (f32path) {
    float* hs = (float*)rest;
    k_lstm<float><<<dim3(NB), dim3(TPB), 0, stream>>>(
        tokens, G, hbuf, hs, Uf, Ui, Uc, Uo, bUf, bUi, bUc, bUo);
    k_out_gemm<float><<<dim3(T_SEQ / 64, VOCAB / 128), dim3(256), 0, stream>>>(
        hs, V, bv, logits);
  } else {
    u16* hs = (u16*)rest;
    k_lstm<u16><<<dim3(NB), dim3(TPB), 0, stream>>>(
        tokens, G, hbuf, hs, Uf, Ui, Uc, Uo, bUf, bUi, bUc, bUo);
    k_out_gemm<u16><<<dim3(T_SEQ / 64, VOCAB / 128), dim3(256), 0, stream>>>(
        hs, V, bv, logits);
  }
  k_logsoftmax<<<dim3(T_SEQ), dim3(256), 0, stream>>>(logits);
}